// Round 1
// baseline (355.816 us; speedup 1.0000x reference)
//
#include <hip/hip_runtime.h>
#include <stdint.h>

typedef unsigned short u16;
typedef __bf16 bf16x8 __attribute__((ext_vector_type(8)));
typedef float f32x4 __attribute__((ext_vector_type(4)));

#define D_MODEL 1024
#define NHEADS  16
#define DHEAD   64
#define BATCH   8
#define SEQ     1024
#define MTOT    (BATCH*SEQ)          // 8192 rows

__device__ __forceinline__ u16 f2bf(float f) {
    union { float f; uint32_t u; } v; v.f = f;
    uint32_t u = v.u;
    u += 0x7fffu + ((u >> 16) & 1u);  // RNE
    return (u16)(u >> 16);
}

// ---------------------------------------------------------------- LayerNorm
__global__ __launch_bounds__(256) void ln_kernel(
    const float* __restrict__ z, const float* __restrict__ w,
    const float* __restrict__ b, u16* __restrict__ zn)
{
    const int row = blockIdx.x;
    const int t = threadIdx.x;
    const float4 v = reinterpret_cast<const float4*>(z + (size_t)row * D_MODEL)[t];
    float s  = v.x + v.y + v.z + v.w;
    float s2 = v.x*v.x + v.y*v.y + v.z*v.z + v.w*v.w;
    #pragma unroll
    for (int off = 32; off; off >>= 1) {
        s  += __shfl_down(s,  off, 64);
        s2 += __shfl_down(s2, off, 64);
    }
    __shared__ float red[8];
    const int wave = t >> 6, lane = t & 63;
    if (lane == 0) { red[wave] = s; red[wave + 4] = s2; }
    __syncthreads();
    if (t == 0) {
        float ts  = red[0] + red[1] + red[2] + red[3];
        float ts2 = red[4] + red[5] + red[6] + red[7];
        float mu  = ts * (1.0f / D_MODEL);
        float var = ts2 * (1.0f / D_MODEL) - mu * mu;
        red[0] = mu; red[1] = rsqrtf(var + 1e-5f);
    }
    __syncthreads();
    const float mu = red[0], rstd = red[1];
    const float4 wv = reinterpret_cast<const float4*>(w)[t];
    const float4 bv = reinterpret_cast<const float4*>(b)[t];
    ushort4 o;
    o.x = f2bf((v.x - mu) * rstd * wv.x + bv.x);
    o.y = f2bf((v.y - mu) * rstd * wv.y + bv.y);
    o.z = f2bf((v.z - mu) * rstd * wv.z + bv.z);
    o.w = f2bf((v.w - mu) * rstd * wv.w + bv.w);
    reinterpret_cast<ushort4*>(zn + (size_t)row * D_MODEL)[t] = o;
}

// ----------------------------------------------- weight transpose + bf16 cast
// in [R][C] fp32 -> out [C][R] bf16
__global__ __launch_bounds__(256) void transpose_cast(
    const float* __restrict__ in, u16* __restrict__ out, int R, int C)
{
    __shared__ u16 tile[32][33];
    const int c0 = blockIdx.x * 32, r0 = blockIdx.y * 32;
    const int tx = threadIdx.x & 31, ty = threadIdx.x >> 5;   // 32x8
    #pragma unroll
    for (int i = 0; i < 4; ++i)
        tile[ty + i*8][tx] = f2bf(in[(size_t)(r0 + ty + i*8) * C + c0 + tx]);
    __syncthreads();
    #pragma unroll
    for (int i = 0; i < 4; ++i)
        out[(size_t)(c0 + ty + i*8) * R + r0 + tx] = tile[tx][ty + i*8];
}

// ---------------------------------------------------------------- GEMM core
// A [M][1024] bf16 row-major, Bt [N][1024] bf16 (B transposed), 128x128 tile,
// 4 waves, each 64x64 (4x4 MFMA tiles of 16x16x32).
#define LDSP 40   // 32 + 8 pad halves -> 80B row stride (2-way max bank alias)

#define GEMM_MAINLOOP(A_, Bt_)                                                  \
    __shared__ u16 As[128 * LDSP];                                              \
    __shared__ u16 Bs[128 * LDSP];                                              \
    const int tid = threadIdx.x;                                                \
    const int wave = tid >> 6, lane = tid & 63;                                 \
    const int lm = lane & 15, lk = (lane >> 4) * 8;                             \
    const int wm = (wave >> 1) * 64, wn = (wave & 1) * 64;                      \
    const int m0 = blockIdx.y * 128, n0 = blockIdx.x * 128;                     \
    f32x4 acc[4][4] = {};                                                       \
    for (int k0 = 0; k0 < D_MODEL; k0 += 32) {                                  \
        _Pragma("unroll")                                                       \
        for (int s = 0; s < 2; ++s) {                                           \
            int slot = tid + s * 256;                                           \
            int row = slot >> 2, seg = slot & 3;                                \
            uint4 av = *reinterpret_cast<const uint4*>(                         \
                &A_[(size_t)(m0 + row) * D_MODEL + k0 + seg * 8]);              \
            uint4 bv = *reinterpret_cast<const uint4*>(                         \
                &Bt_[(size_t)(n0 + row) * D_MODEL + k0 + seg * 8]);             \
            *reinterpret_cast<uint4*>(&As[row * LDSP + seg * 8]) = av;          \
            *reinterpret_cast<uint4*>(&Bs[row * LDSP + seg * 8]) = bv;          \
        }                                                                       \
        __syncthreads();                                                        \
        bf16x8 af[4], bfr[4];                                                   \
        _Pragma("unroll")                                                       \
        for (int i = 0; i < 4; ++i) {                                           \
            af[i]  = *reinterpret_cast<const bf16x8*>(&As[(wm + i*16 + lm) * LDSP + lk]); \
            bfr[i] = *reinterpret_cast<const bf16x8*>(&Bs[(wn + i*16 + lm) * LDSP + lk]); \
        }                                                                       \
        _Pragma("unroll")                                                       \
        for (int i = 0; i < 4; ++i)                                             \
            _Pragma("unroll")                                                   \
            for (int j = 0; j < 4; ++j)                                         \
                acc[i][j] = __builtin_amdgcn_mfma_f32_16x16x32_bf16(            \
                    af[i], bfr[j], acc[i][j], 0, 0, 0);                         \
        __syncthreads();                                                        \
    }

// QKV GEMM: N=3072. Epilogue scatters into q[b,h,t,dh], k[b,h,t,dh], v[b,h,dh,t]
__global__ __launch_bounds__(256, 2) void gemm_qkv(
    const u16* __restrict__ A, const u16* __restrict__ Bt,
    const float* __restrict__ bias,
    u16* __restrict__ q, u16* __restrict__ k, u16* __restrict__ v)
{
    GEMM_MAINLOOP(A, Bt)
    #pragma unroll
    for (int j = 0; j < 4; ++j) {
        const int col = n0 + wn + j * 16 + lm;
        const float bv = bias[col];
        const int sel = col >> 10;          // 0=q 1=k 2=v
        const int c = col & 1023;
        const int h = c >> 6, dh = c & 63;
        #pragma unroll
        for (int i = 0; i < 4; ++i) {
            #pragma unroll
            for (int r = 0; r < 4; ++r) {
                const int m = m0 + wm + i * 16 + (lane >> 4) * 4 + r;
                const int b = m >> 10, t = m & 1023;
                const u16 o = f2bf(acc[i][j][r] + bv);
                const size_t bh = (size_t)(b * NHEADS + h);
                if (sel == 0)      q[(bh * SEQ + t) * DHEAD + dh] = o;
                else if (sel == 1) k[(bh * SEQ + t) * DHEAD + dh] = o;
                else               v[(bh * DHEAD + dh) * SEQ + t] = o;
            }
        }
    }
}

// Proj GEMM: N=1024. Epilogue: out = z + acc + bias (fp32)
__global__ __launch_bounds__(256, 2) void gemm_proj(
    const u16* __restrict__ A, const u16* __restrict__ Bt,
    const float* __restrict__ bias, const float* __restrict__ z,
    float* __restrict__ out)
{
    GEMM_MAINLOOP(A, Bt)
    #pragma unroll
    for (int j = 0; j < 4; ++j) {
        const int col = n0 + wn + j * 16 + lm;
        const float bv = bias[col];
        #pragma unroll
        for (int i = 0; i < 4; ++i) {
            #pragma unroll
            for (int r = 0; r < 4; ++r) {
                const int m = m0 + wm + i * 16 + (lane >> 4) * 4 + r;
                const size_t idx = (size_t)m * D_MODEL + col;
                out[idx] = z[idx] + acc[i][j][r] + bv;
            }
        }
    }
}

// ------------------------------------------------------------ flash attention
// grid (16 q-tiles, 16 heads, 8 batch); 4 waves; wave owns 16 q rows.
#define ALD 72   // 64 + 8 pad halves -> 144B row stride

__global__ __launch_bounds__(256, 2) void attn_kernel(
    const u16* __restrict__ Q, const u16* __restrict__ K,
    const u16* __restrict__ Vt, u16* __restrict__ msa)
{
    __shared__ u16 Ks[64 * ALD];
    __shared__ u16 Vs[64 * ALD];
    __shared__ u16 Ps[64 * ALD];
    const int tid = threadIdx.x, wave = tid >> 6, lane = tid & 63;
    const int lm = lane & 15, lk = (lane >> 4) * 8;
    const int b = blockIdx.z, h = blockIdx.y, q0 = blockIdx.x * 64;
    const size_t headBase = ((size_t)b * NHEADS + h) * SEQ * DHEAD;
    const u16* Qh = Q + headBase;
    const u16* Kh = K + headBase;
    const u16* Vh = Vt + headBase;       // [64 dh][1024 t]

    bf16x8 qf[2];
    {
        const u16* qrow = Qh + (size_t)(q0 + wave * 16 + lm) * DHEAD;
        qf[0] = *reinterpret_cast<const bf16x8*>(qrow + lk);
        qf[1] = *reinterpret_cast<const bf16x8*>(qrow + 32 + lk);
    }

    f32x4 o[4] = {};
    float mrow[4], lrow[4];
    #pragma unroll
    for (int r = 0; r < 4; ++r) { mrow[r] = -__builtin_inff(); lrow[r] = 0.f; }

    for (int j0 = 0; j0 < SEQ; j0 += 64) {
        #pragma unroll
        for (int s = 0; s < 2; ++s) {
            int slot = tid + s * 256;           // 64 rows x 8 segs
            int row = slot >> 3, seg = slot & 7;
            uint4 kv = *reinterpret_cast<const uint4*>(&Kh[(size_t)(j0 + row) * DHEAD + seg * 8]);
            uint4 vv = *reinterpret_cast<const uint4*>(&Vh[(size_t)row * SEQ + j0 + seg * 8]);
            *reinterpret_cast<uint4*>(&Ks[row * ALD + seg * 8]) = kv;
            *reinterpret_cast<uint4*>(&Vs[row * ALD + seg * 8]) = vv;
        }
        __syncthreads();

        f32x4 s[4] = {};
        #pragma unroll
        for (int ni = 0; ni < 4; ++ni) {
            bf16x8 b0 = *reinterpret_cast<const bf16x8*>(&Ks[(ni*16 + lm) * ALD + lk]);
            bf16x8 b1 = *reinterpret_cast<const bf16x8*>(&Ks[(ni*16 + lm) * ALD + 32 + lk]);
            s[ni] = __builtin_amdgcn_mfma_f32_16x16x32_bf16(qf[0], b0, s[ni], 0, 0, 0);
            s[ni] = __builtin_amdgcn_mfma_f32_16x16x32_bf16(qf[1], b1, s[ni], 0, 0, 0);
        }
        #pragma unroll
        for (int ni = 0; ni < 4; ++ni)
            #pragma unroll
            for (int r = 0; r < 4; ++r) s[ni][r] *= 0.125f;   // 1/sqrt(64)

        float mnew[4], alpha[4], rsum[4];
        #pragma unroll
        for (int r = 0; r < 4; ++r) {
            float mx = fmaxf(fmaxf(s[0][r], s[1][r]), fmaxf(s[2][r], s[3][r]));
            mx = fmaxf(mx, __shfl_xor(mx, 1, 64));
            mx = fmaxf(mx, __shfl_xor(mx, 2, 64));
            mx = fmaxf(mx, __shfl_xor(mx, 4, 64));
            mx = fmaxf(mx, __shfl_xor(mx, 8, 64));
            mnew[r] = fmaxf(mrow[r], mx);
            alpha[r] = __expf(mrow[r] - mnew[r]);
            mrow[r] = mnew[r];
            rsum[r] = 0.f;
        }
        const int prow = wave * 16 + (lane >> 4) * 4;
        #pragma unroll
        for (int ni = 0; ni < 4; ++ni) {
            #pragma unroll
            for (int r = 0; r < 4; ++r) {
                float p = __expf(s[ni][r] - mnew[r]);
                rsum[r] += p;
                Ps[(prow + r) * ALD + ni * 16 + lm] = f2bf(p);
            }
        }
        #pragma unroll
        for (int r = 0; r < 4; ++r) {
            float rs = rsum[r];
            rs += __shfl_xor(rs, 1, 64);
            rs += __shfl_xor(rs, 2, 64);
            rs += __shfl_xor(rs, 4, 64);
            rs += __shfl_xor(rs, 8, 64);
            lrow[r] = lrow[r] * alpha[r] + rs;
            #pragma unroll
            for (int ni = 0; ni < 4; ++ni) o[ni][r] *= alpha[r];
        }
        __syncthreads();   // P visible (cross-lane LDS), Ks reads done

        bf16x8 ap0 = *reinterpret_cast<const bf16x8*>(&Ps[(wave*16 + lm) * ALD + lk]);
        bf16x8 ap1 = *reinterpret_cast<const bf16x8*>(&Ps[(wave*16 + lm) * ALD + 32 + lk]);
        #pragma unroll
        for (int ni = 0; ni < 4; ++ni) {
            bf16x8 bv0 = *reinterpret_cast<const bf16x8*>(&Vs[(ni*16 + lm) * ALD + lk]);
            bf16x8 bv1 = *reinterpret_cast<const bf16x8*>(&Vs[(ni*16 + lm) * ALD + 32 + lk]);
            o[ni] = __builtin_amdgcn_mfma_f32_16x16x32_bf16(ap0, bv0, o[ni], 0, 0, 0);
            o[ni] = __builtin_amdgcn_mfma_f32_16x16x32_bf16(ap1, bv1, o[ni], 0, 0, 0);
        }
        __syncthreads();   // Vs/Ps free for next iteration
    }

    #pragma unroll
    for (int r = 0; r < 4; ++r) {
        const int t = q0 + wave * 16 + (lane >> 4) * 4 + r;
        const float inv = 1.0f / lrow[r];
        const size_t rowBase = ((size_t)b * SEQ + t) * D_MODEL + h * DHEAD;
        #pragma unroll
        for (int ni = 0; ni < 4; ++ni)
            msa[rowBase + ni * 16 + lm] = f2bf(o[ni][r] * inv);
    }
}

// -------------------------------------------------------------------- launch
extern "C" void kernel_launch(void* const* d_in, const int* in_sizes, int n_in,
                              void* d_out, int out_size, void* d_ws, size_t ws_size,
                              hipStream_t stream) {
    const float* z      = (const float*)d_in[0];
    const float* ln_w   = (const float*)d_in[1];
    const float* ln_b   = (const float*)d_in[2];
    const float* W_qkv  = (const float*)d_in[3];
    const float* b_qkv  = (const float*)d_in[4];
    const float* W_proj = (const float*)d_in[5];
    const float* b_proj = (const float*)d_in[6];
    float* out = (float*)d_out;

    u16* ws = (u16*)d_ws;
    u16* zn     = ws;                              // [8192][1024]  (aliased as msa later)
    u16* wqkvT  = zn + (size_t)MTOT * D_MODEL;     // [3072][1024]
    u16* wprojT = wqkvT + (size_t)3 * D_MODEL * D_MODEL;  // [1024][1024]
    u16* q      = wprojT + (size_t)D_MODEL * D_MODEL;     // [8][16][1024][64]
    u16* k      = q + (size_t)MTOT * D_MODEL;
    u16* v      = k + (size_t)MTOT * D_MODEL;
    u16* msa    = zn;   // reuse: zn consumed by gemm_qkv before attn writes

    ln_kernel<<<MTOT, 256, 0, stream>>>(z, ln_w, ln_b, zn);
    transpose_cast<<<dim3(3 * D_MODEL / 32, D_MODEL / 32), 256, 0, stream>>>(
        W_qkv, wqkvT, D_MODEL, 3 * D_MODEL);
    transpose_cast<<<dim3(D_MODEL / 32, D_MODEL / 32), 256, 0, stream>>>(
        W_proj, wprojT, D_MODEL, D_MODEL);
    gemm_qkv<<<dim3(3 * D_MODEL / 128, MTOT / 128), 256, 0, stream>>>(
        zn, wqkvT, b_qkv, q, k, v);
    attn_kernel<<<dim3(SEQ / 64, NHEADS, BATCH), 256, 0, stream>>>(q, k, v, msa);
    gemm_proj<<<dim3(D_MODEL / 128, MTOT / 128), 256, 0, stream>>>(
        msa, wprojT, b_proj, z, out);
}

// Round 3
// 321.257 us; speedup vs baseline: 1.1076x; 1.1076x over previous
//
#include <hip/hip_runtime.h>
#include <stdint.h>

typedef unsigned short u16;
typedef __bf16 bf16x8 __attribute__((ext_vector_type(8)));
typedef short s16x4 __attribute__((ext_vector_type(4)));
typedef float f32x4 __attribute__((ext_vector_type(4)));

#define D_MODEL 1024
#define NHEADS  16
#define DHEAD   64
#define BATCH   8
#define SEQ     1024
#define MTOT    (BATCH*SEQ)          // 8192 rows

#define GPTR(p) ((const __attribute__((address_space(1))) void*)(p))
#define LPTR(p) ((__attribute__((address_space(3))) void*)(p))

// 16x16x16 bf16 MFMA. The builtin only exists in the DEVICE pass; host just
// needs to parse. The LLVM spelling on gfx9xx is the _1k one (v4i16 operands).
#if defined(__HIP_DEVICE_COMPILE__)
  #if __has_builtin(__builtin_amdgcn_mfma_f32_16x16x16bf16_1k)
    #define MFMA16(a, b, c) __builtin_amdgcn_mfma_f32_16x16x16bf16_1k((a), (b), (c), 0, 0, 0)
  #else
    __device__ __forceinline__ f32x4 mfma16_asm(s16x4 a, s16x4 b, f32x4 c) {
        asm volatile("v_mfma_f32_16x16x16_bf16 %0, %1, %2, %0"
                     : "+v"(c) : "v"(a), "v"(b));
        return c;
    }
    #define MFMA16(a, b, c) mfma16_asm((a), (b), (c))
  #endif
#else
  #define MFMA16(a, b, c) (c)   // host stub, never executed
#endif

__device__ __forceinline__ u16 f2bf(float f) {
    union { float f; uint32_t u; } v; v.f = f;
    uint32_t u = v.u;
    u += 0x7fffu + ((u >> 16) & 1u);  // RNE
    return (u16)(u >> 16);
}

// ---------------------------------------------------------------- LayerNorm
__global__ __launch_bounds__(256) void ln_kernel(
    const float* __restrict__ z, const float* __restrict__ w,
    const float* __restrict__ b, u16* __restrict__ zn)
{
    const int row = blockIdx.x;
    const int t = threadIdx.x;
    const float4 v = reinterpret_cast<const float4*>(z + (size_t)row * D_MODEL)[t];
    float s  = v.x + v.y + v.z + v.w;
    float s2 = v.x*v.x + v.y*v.y + v.z*v.z + v.w*v.w;
    #pragma unroll
    for (int off = 32; off; off >>= 1) {
        s  += __shfl_down(s,  off, 64);
        s2 += __shfl_down(s2, off, 64);
    }
    __shared__ float red[8];
    const int wave = t >> 6, lane = t & 63;
    if (lane == 0) { red[wave] = s; red[wave + 4] = s2; }
    __syncthreads();
    if (t == 0) {
        float ts  = red[0] + red[1] + red[2] + red[3];
        float ts2 = red[4] + red[5] + red[6] + red[7];
        float mu  = ts * (1.0f / D_MODEL);
        float var = ts2 * (1.0f / D_MODEL) - mu * mu;
        red[0] = mu; red[1] = rsqrtf(var + 1e-5f);
    }
    __syncthreads();
    const float mu = red[0], rstd = red[1];
    const float4 wv = reinterpret_cast<const float4*>(w)[t];
    const float4 bv = reinterpret_cast<const float4*>(b)[t];
    ushort4 o;
    o.x = f2bf((v.x - mu) * rstd * wv.x + bv.x);
    o.y = f2bf((v.y - mu) * rstd * wv.y + bv.y);
    o.z = f2bf((v.z - mu) * rstd * wv.z + bv.z);
    o.w = f2bf((v.w - mu) * rstd * wv.w + bv.w);
    reinterpret_cast<ushort4*>(zn + (size_t)row * D_MODEL)[t] = o;
}

// ----------------------------------------------- weight transpose + bf16 cast
__global__ __launch_bounds__(256) void transpose_cast(
    const float* __restrict__ in, u16* __restrict__ out, int R, int C)
{
    __shared__ u16 tile[32][33];
    const int c0 = blockIdx.x * 32, r0 = blockIdx.y * 32;
    const int tx = threadIdx.x & 31, ty = threadIdx.x >> 5;   // 32x8
    #pragma unroll
    for (int i = 0; i < 4; ++i)
        tile[ty + i*8][tx] = f2bf(in[(size_t)(r0 + ty + i*8) * C + c0 + tx]);
    __syncthreads();
    #pragma unroll
    for (int i = 0; i < 4; ++i)
        out[(size_t)(c0 + ty + i*8) * R + r0 + tx] = tile[tx][ty + i*8];
}

// ---------------------------------------------------------------- GEMM core
// A [M][1024] bf16 row-major, Bt [N][1024] bf16 (B transposed), 128x128 tile,
// 4 waves, each 64x64 (4x4 MFMA tiles of 16x16x32).
// global_load_lds width-16 staging: LDS layout MUST be unpadded/contiguous
// in lane order (wave-uniform base + lane*16B).
#define GEMM_MAINLOOP(A_, Bt_)                                                  \
    __shared__ u16 As[128 * 32];                                                \
    __shared__ u16 Bs[128 * 32];                                                \
    const int tid = threadIdx.x;                                                \
    const int wave = tid >> 6, lane = tid & 63;                                 \
    const int lm = lane & 15, lk = (lane >> 4) * 8;                             \
    const int wm = (wave >> 1) * 64, wn = (wave & 1) * 64;                      \
    const int m0 = blockIdx.y * 128, n0 = blockIdx.x * 128;                     \
    const int srow = wave * 32 + (lane >> 2);                                   \
    const int scol = (lane & 3) * 8;                                            \
    f32x4 acc[4][4] = {};                                                       \
    for (int k0 = 0; k0 < D_MODEL; k0 += 32) {                                  \
        _Pragma("unroll")                                                       \
        for (int c = 0; c < 2; ++c) {                                           \
            const int r = srow + c * 16;                                        \
            __builtin_amdgcn_global_load_lds(                                   \
                GPTR(&A_[(size_t)(m0 + r) * D_MODEL + k0 + scol]),              \
                LPTR(&As[r * 32 + scol]), 16, 0, 0);                            \
            __builtin_amdgcn_global_load_lds(                                   \
                GPTR(&Bt_[(size_t)(n0 + r) * D_MODEL + k0 + scol]),             \
                LPTR(&Bs[r * 32 + scol]), 16, 0, 0);                            \
        }                                                                       \
        __syncthreads();                                                        \
        bf16x8 af[4], bfr[4];                                                   \
        _Pragma("unroll")                                                       \
        for (int i = 0; i < 4; ++i) {                                           \
            af[i]  = *reinterpret_cast<const bf16x8*>(&As[(wm + i*16 + lm) * 32 + lk]); \
            bfr[i] = *reinterpret_cast<const bf16x8*>(&Bs[(wn + i*16 + lm) * 32 + lk]); \
        }                                                                       \
        _Pragma("unroll")                                                       \
        for (int i = 0; i < 4; ++i)                                             \
            _Pragma("unroll")                                                   \
            for (int j = 0; j < 4; ++j)                                         \
                acc[i][j] = __builtin_amdgcn_mfma_f32_16x16x32_bf16(            \
                    af[i], bfr[j], acc[i][j], 0, 0, 0);                         \
        __syncthreads();                                                        \
    }

#define QSCALE 0.180336880f   // 0.125 * log2(e): folded into q for exp2 softmax

// QKV GEMM: N=3072. Epilogue scatters into q[b,h,t,dh], k[b,h,t,dh], v[b,h,dh,t]
__global__ __launch_bounds__(256, 2) void gemm_qkv(
    const u16* __restrict__ A, const u16* __restrict__ Bt,
    const float* __restrict__ bias,
    u16* __restrict__ q, u16* __restrict__ k, u16* __restrict__ v)
{
    GEMM_MAINLOOP(A, Bt)
    #pragma unroll
    for (int j = 0; j < 4; ++j) {
        const int col = n0 + wn + j * 16 + lm;
        const float bv = bias[col];
        const int sel = col >> 10;          // 0=q 1=k 2=v
        const int c = col & 1023;
        const int h = c >> 6, dh = c & 63;
        const float scl = (sel == 0) ? QSCALE : 1.0f;
        #pragma unroll
        for (int i = 0; i < 4; ++i) {
            #pragma unroll
            for (int r = 0; r < 4; ++r) {
                const int m = m0 + wm + i * 16 + (lane >> 4) * 4 + r;
                const int b = m >> 10, t = m & 1023;
                const u16 o = f2bf((acc[i][j][r] + bv) * scl);
                const size_t bh = (size_t)(b * NHEADS + h);
                if (sel == 0)      q[(bh * SEQ + t) * DHEAD + dh] = o;
                else if (sel == 1) k[(bh * SEQ + t) * DHEAD + dh] = o;
                else               v[(bh * DHEAD + dh) * SEQ + t] = o;
            }
        }
    }
}

// Proj GEMM: N=1024. Epilogue: out = z + acc + bias (fp32)
__global__ __launch_bounds__(256, 2) void gemm_proj(
    const u16* __restrict__ A, const u16* __restrict__ Bt,
    const float* __restrict__ bias, const float* __restrict__ z,
    float* __restrict__ out)
{
    GEMM_MAINLOOP(A, Bt)
    #pragma unroll
    for (int j = 0; j < 4; ++j) {
        const int col = n0 + wn + j * 16 + lm;
        const float bv = bias[col];
        #pragma unroll
        for (int i = 0; i < 4; ++i) {
            #pragma unroll
            for (int r = 0; r < 4; ++r) {
                const int m = m0 + wm + i * 16 + (lane >> 4) * 4 + r;
                const size_t idx = (size_t)m * D_MODEL + col;
                out[idx] = z[idx] + acc[i][j][r] + bv;
            }
        }
    }
}

// ------------------------------------------------------------ flash attention
// Transposed-S scheme: S^T = K·Q^T (operand swap), so C-layout gives each lane
// ONE q-row (q=lane&15) and kk=4g+r — P lands directly in the B-operand layout
// of mfma_16x16x16, so PV (O^T = V^T·P^T) needs NO LDS round-trip for P.
// grid (16 q-tiles, 16 heads, 8 batch); 4 waves; wave owns 16 q rows.
#define KLD 68   // 64 + 4 pad halves -> 136B row stride (breaks bank classes)

__global__ __launch_bounds__(256, 2) void attn_kernel(
    const u16* __restrict__ Q, const u16* __restrict__ K,
    const u16* __restrict__ Vt, u16* __restrict__ msa)
{
    __shared__ u16 Ks[64 * KLD];
    __shared__ u16 Vs[64 * KLD];
    const int tid = threadIdx.x, wave = tid >> 6, lane = tid & 63;
    const int lm = lane & 15, g = lane >> 4;
    const int b = blockIdx.z, h = blockIdx.y, q0 = blockIdx.x * 64;
    const size_t headBase = ((size_t)b * NHEADS + h) * SEQ * DHEAD;
    const u16* Qh = Q + headBase;
    const u16* Kh = K + headBase;
    const u16* Vh = Vt + headBase;       // [64 dh][1024 t]

    // Q fragment (B-operand of S^T mfma): identical register data to A-frag(Q)
    bf16x8 qf[2];
    {
        const u16* qrow = Qh + (size_t)(q0 + wave * 16 + lm) * DHEAD;
        qf[0] = *reinterpret_cast<const bf16x8*>(qrow + g * 8);
        qf[1] = *reinterpret_cast<const bf16x8*>(qrow + 32 + g * 8);
    }

    f32x4 o[4] = {};          // O^T[d = mtile*16 + 4g + r][q = lm]
    float mrow = -3.0e38f, lrow = 0.f;   // per-lane scalars: one q-row per lane

    for (int j0 = 0; j0 < SEQ; j0 += 64) {
        #pragma unroll
        for (int s = 0; s < 2; ++s) {
            int slot = tid + s * 256;           // 64 rows x 8 segs
            int row = slot >> 3, seg = slot & 7;
            uint4 kv = *reinterpret_cast<const uint4*>(&Kh[(size_t)(j0 + row) * DHEAD + seg * 8]);
            uint4 vv = *reinterpret_cast<const uint4*>(&Vh[(size_t)row * SEQ + j0 + seg * 8]);
            *reinterpret_cast<uint4*>(&Ks[row * KLD + seg * 8]) = kv;
            *reinterpret_cast<uint4*>(&Vs[row * KLD + seg * 8]) = vv;
        }
        __syncthreads();

        // S^T tiles: st[ni][r] = S^T[kk = ni*16 + 4g + r][q = lm] (pre-scaled by QSCALE)
        f32x4 st[4] = {};
        #pragma unroll
        for (int ni = 0; ni < 4; ++ni) {
            bf16x8 k0f = *reinterpret_cast<const bf16x8*>(&Ks[(ni*16 + lm) * KLD + g * 8]);
            bf16x8 k1f = *reinterpret_cast<const bf16x8*>(&Ks[(ni*16 + lm) * KLD + 32 + g * 8]);
            st[ni] = __builtin_amdgcn_mfma_f32_16x16x32_bf16(k0f, qf[0], st[ni], 0, 0, 0);
            st[ni] = __builtin_amdgcn_mfma_f32_16x16x32_bf16(k1f, qf[1], st[ni], 0, 0, 0);
        }

        // online softmax in log2 domain; row = q = lm, distributed over lane>>4 groups
        float mx = st[0][0];
        #pragma unroll
        for (int ni = 0; ni < 4; ++ni)
            #pragma unroll
            for (int r = 0; r < 4; ++r) mx = fmaxf(mx, st[ni][r]);
        mx = fmaxf(mx, __shfl_xor(mx, 16, 64));
        mx = fmaxf(mx, __shfl_xor(mx, 32, 64));
        const float mnew = fmaxf(mrow, mx);
        const float alpha = exp2f(mrow - mnew);
        mrow = mnew;

        float rsum = 0.f;
        s16x4 pfrag[4];
        #pragma unroll
        for (int ni = 0; ni < 4; ++ni) {
            #pragma unroll
            for (int r = 0; r < 4; ++r) {
                float p = exp2f(st[ni][r] - mnew);
                rsum += p;
                pfrag[ni][r] = (short)f2bf(p);
            }
        }
        rsum += __shfl_xor(rsum, 16, 64);
        rsum += __shfl_xor(rsum, 32, 64);
        lrow = lrow * alpha + rsum;

        #pragma unroll
        for (int mt = 0; mt < 4; ++mt)
            #pragma unroll
            for (int r = 0; r < 4; ++r) o[mt][r] *= alpha;

        // O^T += V^T · P^T : A-frag = V^T[d][kk] from Vs, B-frag = pfrag (registers!)
        #pragma unroll
        for (int mt = 0; mt < 4; ++mt) {
            #pragma unroll
            for (int ks = 0; ks < 4; ++ks) {
                s16x4 vf = *reinterpret_cast<const s16x4*>(
                    &Vs[(mt*16 + lm) * KLD + ks*16 + g*4]);
                o[mt] = MFMA16(vf, pfrag[ks], o[mt]);
            }
        }
        __syncthreads();   // Ks/Vs free for next iteration
    }

    const float inv = 1.0f / lrow;
    const int t = q0 + wave * 16 + lm;
    const size_t base = ((size_t)b * SEQ + t) * D_MODEL + h * DHEAD;
    #pragma unroll
    for (int mt = 0; mt < 4; ++mt) {
        const int d0 = mt * 16 + 4 * g;
        ushort4 pk;
        pk.x = f2bf(o[mt][0] * inv);
        pk.y = f2bf(o[mt][1] * inv);
        pk.z = f2bf(o[mt][2] * inv);
        pk.w = f2bf(o[mt][3] * inv);
        *reinterpret_cast<ushort4*>(&msa[base + d0]) = pk;
    }
}

// -------------------------------------------------------------------- launch
extern "C" void kernel_launch(void* const* d_in, const int* in_sizes, int n_in,
                              void* d_out, int out_size, void* d_ws, size_t ws_size,
                              hipStream_t stream) {
    const float* z      = (const float*)d_in[0];
    const float* ln_w   = (const float*)d_in[1];
    const float* ln_b   = (const float*)d_in[2];
    const float* W_qkv  = (const float*)d_in[3];
    const float* b_qkv  = (const float*)d_in[4];
    const float* W_proj = (const float*)d_in[5];
    const float* b_proj = (const float*)d_in[6];
    float* out = (float*)d_out;

    u16* ws = (u16*)d_ws;
    u16* zn     = ws;                              // [8192][1024]  (aliased as msa later)
    u16* wqkvT  = zn + (size_t)MTOT * D_MODEL;     // [3072][1024]
    u16* wprojT = wqkvT + (size_t)3 * D_MODEL * D_MODEL;  // [1024][1024]
    u16* q      = wprojT + (size_t)D_MODEL * D_MODEL;     // [8][16][1024][64]
    u16* k      = q + (size_t)MTOT * D_MODEL;
    u16* v      = k + (size_t)MTOT * D_MODEL;
    u16* msa    = zn;   // reuse: zn consumed by gemm_qkv before attn writes

    ln_kernel<<<MTOT, 256, 0, stream>>>(z, ln_w, ln_b, zn);
    transpose_cast<<<dim3(3 * D_MODEL / 32, D_MODEL / 32), 256, 0, stream>>>(
        W_qkv, wqkvT, D_MODEL, 3 * D_MODEL);
    transpose_cast<<<dim3(D_MODEL / 32, D_MODEL / 32), 256, 0, stream>>>(
        W_proj, wprojT, D_MODEL, D_MODEL);
    gemm_qkv<<<dim3(3 * D_MODEL / 128, MTOT / 128), 256, 0, stream>>>(
        zn, wqkvT, b_qkv, q, k, v);
    attn_kernel<<<dim3(SEQ / 64, NHEADS, BATCH), 256, 0, stream>>>(q, k, v, msa);
    gemm_proj<<<dim3(D_MODEL / 128, MTOT / 128), 256, 0, stream>>>(
        msa, wprojT, b_proj, z, out);
}

// Round 4
// 295.873 us; speedup vs baseline: 1.2026x; 1.0858x over previous
//
#include <hip/hip_runtime.h>
#include <stdint.h>

typedef unsigned short u16;
typedef __bf16 bf16x8 __attribute__((ext_vector_type(8)));
typedef short s16x4 __attribute__((ext_vector_type(4)));
typedef float f32x4 __attribute__((ext_vector_type(4)));

#define D_MODEL 1024
#define NHEADS  16
#define DHEAD   64
#define BATCH   8
#define SEQ     1024
#define MTOT    (BATCH*SEQ)          // 8192 rows

#define GPTR(p) ((const __attribute__((address_space(1))) void*)(p))
#define LPTR(p) ((__attribute__((address_space(3))) void*)(p))

// 16x16x16 bf16 MFMA. Builtin exists only in the DEVICE pass; host just parses.
#if defined(__HIP_DEVICE_COMPILE__)
  #if __has_builtin(__builtin_amdgcn_mfma_f32_16x16x16bf16_1k)
    #define MFMA16(a, b, c) __builtin_amdgcn_mfma_f32_16x16x16bf16_1k((a), (b), (c), 0, 0, 0)
  #else
    __device__ __forceinline__ f32x4 mfma16_asm(s16x4 a, s16x4 b, f32x4 c) {
        asm volatile("v_mfma_f32_16x16x16_bf16 %0, %1, %2, %0"
                     : "+v"(c) : "v"(a), "v"(b));
        return c;
    }
    #define MFMA16(a, b, c) mfma16_asm((a), (b), (c))
  #endif
#else
  #define MFMA16(a, b, c) (c)   // host stub, never executed
#endif

__device__ __forceinline__ u16 f2bf(float f) {
    union { float f; uint32_t u; } v; v.f = f;
    uint32_t u = v.u;
    u += 0x7fffu + ((u >> 16) & 1u);  // RNE
    return (u16)(u >> 16);
}

// ---------------------------------------------------------------- LayerNorm
__global__ __launch_bounds__(256) void ln_kernel(
    const float* __restrict__ z, const float* __restrict__ w,
    const float* __restrict__ b, u16* __restrict__ zn)
{
    const int row = blockIdx.x;
    const int t = threadIdx.x;
    const float4 v = reinterpret_cast<const float4*>(z + (size_t)row * D_MODEL)[t];
    float s  = v.x + v.y + v.z + v.w;
    float s2 = v.x*v.x + v.y*v.y + v.z*v.z + v.w*v.w;
    #pragma unroll
    for (int off = 32; off; off >>= 1) {
        s  += __shfl_down(s,  off, 64);
        s2 += __shfl_down(s2, off, 64);
    }
    __shared__ float red[8];
    const int wave = t >> 6, lane = t & 63;
    if (lane == 0) { red[wave] = s; red[wave + 4] = s2; }
    __syncthreads();
    if (t == 0) {
        float ts  = red[0] + red[1] + red[2] + red[3];
        float ts2 = red[4] + red[5] + red[6] + red[7];
        float mu  = ts * (1.0f / D_MODEL);
        float var = ts2 * (1.0f / D_MODEL) - mu * mu;
        red[0] = mu; red[1] = rsqrtf(var + 1e-5f);
    }
    __syncthreads();
    const float mu = red[0], rstd = red[1];
    const float4 wv = reinterpret_cast<const float4*>(w)[t];
    const float4 bv = reinterpret_cast<const float4*>(b)[t];
    ushort4 o;
    o.x = f2bf((v.x - mu) * rstd * wv.x + bv.x);
    o.y = f2bf((v.y - mu) * rstd * wv.y + bv.y);
    o.z = f2bf((v.z - mu) * rstd * wv.z + bv.z);
    o.w = f2bf((v.w - mu) * rstd * wv.w + bv.w);
    reinterpret_cast<ushort4*>(zn + (size_t)row * D_MODEL)[t] = o;
}

// ----------------------------------------------- weight transpose + bf16 cast
__global__ __launch_bounds__(256) void transpose_cast(
    const float* __restrict__ in, u16* __restrict__ out, int R, int C)
{
    __shared__ u16 tile[32][33];
    const int c0 = blockIdx.x * 32, r0 = blockIdx.y * 32;
    const int tx = threadIdx.x & 31, ty = threadIdx.x >> 5;   // 32x8
    #pragma unroll
    for (int i = 0; i < 4; ++i)
        tile[ty + i*8][tx] = f2bf(in[(size_t)(r0 + ty + i*8) * C + c0 + tx]);
    __syncthreads();
    #pragma unroll
    for (int i = 0; i < 4; ++i)
        out[(size_t)(c0 + ty + i*8) * R + r0 + tx] = tile[tx][ty + i*8];
}

// -------------------------------------------------- V transpose: [b,h,t,dh] -> [b,h,dh,t]
__global__ __launch_bounds__(256) void transpose_v(
    const u16* __restrict__ in, u16* __restrict__ out)
{
    __shared__ u16 tile[64][65];
    const int bh = blockIdx.y;          // 0..127
    const int t0 = blockIdx.x * 64;     // 16 t-tiles
    const int tid = threadIdx.x;
    const u16* src = in + ((size_t)bh * SEQ + t0) * DHEAD;
    #pragma unroll
    for (int i = 0; i < 4; ++i) {
        const int row = (tid >> 4) + i * 16;       // t within tile
        const int c4  = (tid & 15) * 4;            // dh chunk
        *reinterpret_cast<ushort4*>(&tile[row][c4]) =
            *reinterpret_cast<const ushort4*>(&src[(size_t)row * DHEAD + c4]);
    }
    __syncthreads();
    u16* dst = out + (size_t)bh * DHEAD * SEQ + t0;
    #pragma unroll
    for (int i = 0; i < 4; ++i) {
        const int dh = (tid >> 4) + i * 16;
        const int tt = (tid & 15) * 4;
        ushort4 o;
        o.x = tile[tt+0][dh]; o.y = tile[tt+1][dh];
        o.z = tile[tt+2][dh]; o.w = tile[tt+3][dh];
        *reinterpret_cast<ushort4*>(&dst[(size_t)dh * SEQ + tt]) = o;
    }
}

// ---------------------------------------------------------------- GEMM core
// A [M][1024] bf16 row-major, Bt [N][1024] bf16, 128x128 tile, BK=64, 4 waves.
// global_load_lds width-16 staging (dest MUST be wave-uniform base + lane*16B).
// XOR swizzle: LDS slot (row, seg) holds global chunk seg^(row&7) -> fragment
// reads hit all 32 banks (was 8-way conflict unswizzled). Read chunk index
// (ko*4+g)^(lm&7) is a per-lane CONSTANT (wm,wn,i*16 are multiples of 16).
// MFMA operands are SWAPPED (bfr first): acc[i][j][r] = C[m0+wm+i*16+lm]
// [n0+wn+j*16+4g+r] -> each lane owns 4 consecutive cols: vectorized epilogue.
#define GEMM_MAINLOOP(A_, Bt_)                                                  \
    __shared__ u16 As[128 * 64];                                                \
    __shared__ u16 Bs[128 * 64];                                                \
    const int tid = threadIdx.x;                                                \
    const int wave = tid >> 6, lane = tid & 63;                                 \
    const int lm = lane & 15, g = lane >> 4;                                    \
    const int wm = (wave >> 1) * 64, wn = (wave & 1) * 64;                      \
    const int m0 = blockIdx.y * 128, n0 = blockIdx.x * 128;                     \
    const int srow = tid >> 3;                 /* 0..31 */                      \
    const int sseg = tid & 7;                                                   \
    const int sgcol = (sseg ^ (srow & 7)) * 8; /* swizzled global chunk */      \
    const int xl = lm & 7;                                                      \
    f32x4 acc[4][4] = {};                                                       \
    for (int k0 = 0; k0 < D_MODEL; k0 += 64) {                                  \
        _Pragma("unroll")                                                       \
        for (int c = 0; c < 4; ++c) {                                           \
            const int r = srow + c * 32;                                        \
            __builtin_amdgcn_global_load_lds(                                   \
                GPTR(&A_[(size_t)(m0 + r) * D_MODEL + k0 + sgcol]),             \
                LPTR(&As[r * 64 + sseg * 8]), 16, 0, 0);                        \
            __builtin_amdgcn_global_load_lds(                                   \
                GPTR(&Bt_[(size_t)(n0 + r) * D_MODEL + k0 + sgcol]),            \
                LPTR(&Bs[r * 64 + sseg * 8]), 16, 0, 0);                        \
        }                                                                       \
        __syncthreads();                                                        \
        _Pragma("unroll")                                                       \
        for (int ko = 0; ko < 2; ++ko) {                                        \
            const int ca = ((ko * 4 + g) ^ xl) * 8;                             \
            bf16x8 af[4], bfr[4];                                               \
            _Pragma("unroll")                                                   \
            for (int i = 0; i < 4; ++i) {                                       \
                af[i]  = *reinterpret_cast<const bf16x8*>(                      \
                    &As[(wm + i*16 + lm) * 64 + ca]);                           \
                bfr[i] = *reinterpret_cast<const bf16x8*>(                      \
                    &Bs[(wn + i*16 + lm) * 64 + ca]);                           \
            }                                                                   \
            _Pragma("unroll")                                                   \
            for (int i = 0; i < 4; ++i)                                         \
                _Pragma("unroll")                                               \
                for (int j = 0; j < 4; ++j)                                     \
                    acc[i][j] = __builtin_amdgcn_mfma_f32_16x16x32_bf16(        \
                        bfr[j], af[i], acc[i][j], 0, 0, 0);                     \
        }                                                                       \
        __syncthreads();                                                        \
    }

#define QSCALE 0.180336880f   // 0.125 * log2(e): folded into q for exp2 softmax

// QKV GEMM: N=3072. q,k,v all stored [b,h,t,dh] (v transposed later).
__global__ __launch_bounds__(256, 2) void gemm_qkv(
    const u16* __restrict__ A, const u16* __restrict__ Bt,
    const float* __restrict__ bias,
    u16* __restrict__ q, u16* __restrict__ k, u16* __restrict__ v)
{
    GEMM_MAINLOOP(A, Bt)
    const int colbase = n0 + wn;            // multiple of 64
    const int sel = colbase >> 10;          // wave-uniform: 0=q 1=k 2=v
    const int h = (colbase & 1023) >> 6;    // wave-uniform head
    u16* dst = (sel == 0) ? q : (sel == 1) ? k : v;
    const float scl = (sel == 0) ? QSCALE : 1.0f;
    #pragma unroll
    for (int j = 0; j < 4; ++j) {
        const int dh0 = j * 16 + 4 * g;                    // 0..63, 4-aligned
        const float4 bv4 = *reinterpret_cast<const float4*>(&bias[colbase + dh0]);
        #pragma unroll
        for (int i = 0; i < 4; ++i) {
            const int m = m0 + wm + i * 16 + lm;
            const int b = m >> 10, t = m & 1023;
            ushort4 o;
            o.x = f2bf((acc[i][j][0] + bv4.x) * scl);
            o.y = f2bf((acc[i][j][1] + bv4.y) * scl);
            o.z = f2bf((acc[i][j][2] + bv4.z) * scl);
            o.w = f2bf((acc[i][j][3] + bv4.w) * scl);
            *reinterpret_cast<ushort4*>(
                &dst[(((size_t)(b * NHEADS + h)) * SEQ + t) * DHEAD + dh0]) = o;
        }
    }
}

// Proj GEMM: N=1024. Epilogue: out = z + acc + bias (fp32, float4)
__global__ __launch_bounds__(256, 2) void gemm_proj(
    const u16* __restrict__ A, const u16* __restrict__ Bt,
    const float* __restrict__ bias, const float* __restrict__ z,
    float* __restrict__ out)
{
    GEMM_MAINLOOP(A, Bt)
    #pragma unroll
    for (int j = 0; j < 4; ++j) {
        const int col0 = n0 + wn + j * 16 + 4 * g;
        const float4 bv4 = *reinterpret_cast<const float4*>(&bias[col0]);
        #pragma unroll
        for (int i = 0; i < 4; ++i) {
            const int m = m0 + wm + i * 16 + lm;
            const size_t idx = (size_t)m * D_MODEL + col0;
            const float4 zv = *reinterpret_cast<const float4*>(&z[idx]);
            float4 ov;
            ov.x = zv.x + acc[i][j][0] + bv4.x;
            ov.y = zv.y + acc[i][j][1] + bv4.y;
            ov.z = zv.z + acc[i][j][2] + bv4.z;
            ov.w = zv.w + acc[i][j][3] + bv4.w;
            *reinterpret_cast<float4*>(&out[idx]) = ov;
        }
    }
}

// ------------------------------------------------------------ flash attention
// Transposed-S scheme: S^T = K·Q^T (operand swap) -> each lane owns ONE q-row;
// P lands directly in the B-operand layout of mfma_16x16x16 (no LDS round-trip).
#define KLD 68   // 64 + 4 pad halves -> 136B row stride (breaks bank classes)

__global__ __launch_bounds__(256, 2) void attn_kernel(
    const u16* __restrict__ Q, const u16* __restrict__ K,
    const u16* __restrict__ Vt, u16* __restrict__ msa)
{
    __shared__ u16 Ks[64 * KLD];
    __shared__ u16 Vs[64 * KLD];
    const int tid = threadIdx.x, wave = tid >> 6, lane = tid & 63;
    const int lm = lane & 15, g = lane >> 4;
    const int b = blockIdx.z, h = blockIdx.y, q0 = blockIdx.x * 64;
    const size_t headBase = ((size_t)b * NHEADS + h) * SEQ * DHEAD;
    const u16* Qh = Q + headBase;
    const u16* Kh = K + headBase;
    const u16* Vh = Vt + headBase;       // [64 dh][1024 t]

    bf16x8 qf[2];
    {
        const u16* qrow = Qh + (size_t)(q0 + wave * 16 + lm) * DHEAD;
        qf[0] = *reinterpret_cast<const bf16x8*>(qrow + g * 8);
        qf[1] = *reinterpret_cast<const bf16x8*>(qrow + 32 + g * 8);
    }

    f32x4 o[4] = {};          // O^T[d = mt*16 + 4g + r][q = lm]
    float mrow = -3.0e38f, lrow = 0.f;

    for (int j0 = 0; j0 < SEQ; j0 += 64) {
        #pragma unroll
        for (int s = 0; s < 2; ++s) {
            int slot = tid + s * 256;           // 64 rows x 8 segs
            int row = slot >> 3, seg = slot & 7;
            uint4 kv = *reinterpret_cast<const uint4*>(&Kh[(size_t)(j0 + row) * DHEAD + seg * 8]);
            uint4 vv = *reinterpret_cast<const uint4*>(&Vh[(size_t)row * SEQ + j0 + seg * 8]);
            *reinterpret_cast<uint4*>(&Ks[row * KLD + seg * 8]) = kv;
            *reinterpret_cast<uint4*>(&Vs[row * KLD + seg * 8]) = vv;
        }
        __syncthreads();

        f32x4 st[4] = {};
        #pragma unroll
        for (int ni = 0; ni < 4; ++ni) {
            bf16x8 k0f = *reinterpret_cast<const bf16x8*>(&Ks[(ni*16 + lm) * KLD + g * 8]);
            bf16x8 k1f = *reinterpret_cast<const bf16x8*>(&Ks[(ni*16 + lm) * KLD + 32 + g * 8]);
            st[ni] = __builtin_amdgcn_mfma_f32_16x16x32_bf16(k0f, qf[0], st[ni], 0, 0, 0);
            st[ni] = __builtin_amdgcn_mfma_f32_16x16x32_bf16(k1f, qf[1], st[ni], 0, 0, 0);
        }

        float mx = st[0][0];
        #pragma unroll
        for (int ni = 0; ni < 4; ++ni)
            #pragma unroll
            for (int r = 0; r < 4; ++r) mx = fmaxf(mx, st[ni][r]);
        mx = fmaxf(mx, __shfl_xor(mx, 16, 64));
        mx = fmaxf(mx, __shfl_xor(mx, 32, 64));
        const float mnew = fmaxf(mrow, mx);
        const float alpha = exp2f(mrow - mnew);
        mrow = mnew;

        float rsum = 0.f;
        s16x4 pfrag[4];
        #pragma unroll
        for (int ni = 0; ni < 4; ++ni) {
            #pragma unroll
            for (int r = 0; r < 4; ++r) {
                float p = exp2f(st[ni][r] - mnew);
                rsum += p;
                pfrag[ni][r] = (short)f2bf(p);
            }
        }
        rsum += __shfl_xor(rsum, 16, 64);
        rsum += __shfl_xor(rsum, 32, 64);
        lrow = lrow * alpha + rsum;

        #pragma unroll
        for (int mt = 0; mt < 4; ++mt)
            #pragma unroll
            for (int r = 0; r < 4; ++r) o[mt][r] *= alpha;

        #pragma unroll
        for (int mt = 0; mt < 4; ++mt) {
            #pragma unroll
            for (int ks = 0; ks < 4; ++ks) {
                s16x4 vf = *reinterpret_cast<const s16x4*>(
                    &Vs[(mt*16 + lm) * KLD + ks*16 + g*4]);
                o[mt] = MFMA16(vf, pfrag[ks], o[mt]);
            }
        }
        __syncthreads();
    }

    const float inv = 1.0f / lrow;
    const int t = q0 + wave * 16 + lm;
    const size_t base = ((size_t)b * SEQ + t) * D_MODEL + h * DHEAD;
    #pragma unroll
    for (int mt = 0; mt < 4; ++mt) {
        const int d0 = mt * 16 + 4 * g;
        ushort4 pk;
        pk.x = f2bf(o[mt][0] * inv);
        pk.y = f2bf(o[mt][1] * inv);
        pk.z = f2bf(o[mt][2] * inv);
        pk.w = f2bf(o[mt][3] * inv);
        *reinterpret_cast<ushort4*>(&msa[base + d0]) = pk;
    }
}

// -------------------------------------------------------------------- launch
extern "C" void kernel_launch(void* const* d_in, const int* in_sizes, int n_in,
                              void* d_out, int out_size, void* d_ws, size_t ws_size,
                              hipStream_t stream) {
    const float* z      = (const float*)d_in[0];
    const float* ln_w   = (const float*)d_in[1];
    const float* ln_b   = (const float*)d_in[2];
    const float* W_qkv  = (const float*)d_in[3];
    const float* b_qkv  = (const float*)d_in[4];
    const float* W_proj = (const float*)d_in[5];
    const float* b_proj = (const float*)d_in[6];
    float* out = (float*)d_out;

    u16* ws = (u16*)d_ws;
    u16* zn     = ws;                              // [8192][1024] (aliased as msa later)
    u16* wqkvT  = zn + (size_t)MTOT * D_MODEL;     // [3072][1024]
    u16* wprojT = wqkvT + (size_t)3 * D_MODEL * D_MODEL;  // [1024][1024]
    u16* q      = wprojT + (size_t)D_MODEL * D_MODEL;     // [8][16][1024][64]
    u16* k      = q + (size_t)MTOT * D_MODEL;
    u16* vtmp   = k + (size_t)MTOT * D_MODEL;      // [b,h,t,dh]
    u16* vT     = vtmp + (size_t)MTOT * D_MODEL;   // [b,h,dh,t]
    u16* msa    = zn;   // reuse: zn consumed by gemm_qkv before attn writes

    ln_kernel<<<MTOT, 256, 0, stream>>>(z, ln_w, ln_b, zn);
    transpose_cast<<<dim3(3 * D_MODEL / 32, D_MODEL / 32), 256, 0, stream>>>(
        W_qkv, wqkvT, D_MODEL, 3 * D_MODEL);
    transpose_cast<<<dim3(D_MODEL / 32, D_MODEL / 32), 256, 0, stream>>>(
        W_proj, wprojT, D_MODEL, D_MODEL);
    gemm_qkv<<<dim3(3 * D_MODEL / 128, MTOT / 128), 256, 0, stream>>>(
        zn, wqkvT, b_qkv, q, k, vtmp);
    transpose_v<<<dim3(SEQ / 64, BATCH * NHEADS), 256, 0, stream>>>(vtmp, vT);
    attn_kernel<<<dim3(SEQ / 64, NHEADS, BATCH), 256, 0, stream>>>(q, k, vT, msa);
    gemm_proj<<<dim3(D_MODEL / 128, MTOT / 128), 256, 0, stream>>>(
        msa, wprojT, b_proj, z, out);
}